// Round 3
// baseline (441.360 us; speedup 1.0000x reference)
//
#include <hip/hip_runtime.h>

#define L 4096
#define D 512
#define NCH 16   // context n-chunks

typedef __bf16 bf16x8 __attribute__((ext_vector_type(8)));
typedef float  f32x4  __attribute__((ext_vector_type(4)));

__device__ __forceinline__ void load_lds16(const void* g, void* l) {
    __builtin_amdgcn_global_load_lds(
        (const __attribute__((address_space(1))) void*)g,
        (__attribute__((address_space(3))) void*)l, 16, 0, 0);
}

// ---------------------------------------------------------------------------
// f32 -> bf16 conversion (8 elems / thread, 16B stores)
// ---------------------------------------------------------------------------
__global__ __launch_bounds__(256) void f32_to_bf16(const float* __restrict__ in,
                                                   __bf16* __restrict__ out, int n8) {
    int i = blockIdx.x * 256 + threadIdx.x;
    if (i >= n8) return;
    const float4* p = (const float4*)in + (size_t)i * 2;
    float4 a = p[0], b = p[1];
    bf16x8 o = {(__bf16)a.x, (__bf16)a.y, (__bf16)a.z, (__bf16)a.w,
                (__bf16)b.x, (__bf16)b.y, (__bf16)b.z, (__bf16)b.w};
    *(bf16x8*)(out + (size_t)i * 8) = o;
}

// ---------------------------------------------------------------------------
// Generic TN bf16 MFMA GEMM: C[b][m][n] = sum_k A[b][m][k] * B[b][n][k] (+bias[n])
// 128x128 tile, BK=32, 4 waves. XOR-swizzled LDS: slot (row,c) holds global
// chunk c ^ ((row>>1)&3) -> fragment reads hit 8 banks / 2 lanes each (free).
// ---------------------------------------------------------------------------
template <int M, int N, int K>
__global__ __launch_bounds__(256) void gemm_bf16_mfma(
    const __bf16* __restrict__ A, size_t aStride,
    const __bf16* __restrict__ B, size_t bStride,
    float* __restrict__ C, size_t cStride,
    const float* __restrict__ bias) {
    __shared__ __align__(16) __bf16 sA[128 * 32];
    __shared__ __align__(16) __bf16 sB[128 * 32];
    const int b  = blockIdx.z;
    const int m0 = blockIdx.y * 128;
    const int n0 = blockIdx.x * 128;
    const int t    = threadIdx.x;
    const int wave = t >> 6, lane = t & 63;
    const int wm = (wave & 1) * 64, wn = (wave >> 1) * 64;
    const __bf16* Ab = A + (size_t)b * aStride;
    const __bf16* Bb = B + (size_t)b * bStride;
    float* Cb = C + (size_t)b * cStride;

    f32x4 acc[4][4];
#pragma unroll
    for (int i = 0; i < 4; i++)
#pragma unroll
        for (int j = 0; j < 4; j++) acc[i][j] = (f32x4)(0.0f);

    const int fr = lane & 15;            // m (A) / n (B) within 16-tile
    const int cq = lane >> 4;            // k-chunk 0..3 wanted by this lane
    const int ko = (cq ^ ((fr >> 1) & 3)) * 8;  // swizzled LDS k-offset

    for (int k0 = 0; k0 < K; k0 += 32) {
        __syncthreads();
#pragma unroll
        for (int c = 0; c < 2; c++) {
            const int idx = c * 256 + t;
            const int row = idx >> 2, cc = idx & 3;
            const int scc = cc ^ ((row >> 1) & 3);   // source chunk for this slot
            load_lds16(Ab + (size_t)(m0 + row) * K + k0 + scc * 8, &sA[idx * 8]);
            load_lds16(Bb + (size_t)(n0 + row) * K + k0 + scc * 8, &sB[idx * 8]);
        }
        __syncthreads();
        bf16x8 af[4], bfr[4];
#pragma unroll
        for (int i = 0; i < 4; i++) {
            af[i]  = *(const bf16x8*)&sA[(wm + i * 16 + fr) * 32 + ko];
            bfr[i] = *(const bf16x8*)&sB[(wn + i * 16 + fr) * 32 + ko];
        }
#pragma unroll
        for (int i = 0; i < 4; i++)
#pragma unroll
            for (int j = 0; j < 4; j++)
                acc[i][j] = __builtin_amdgcn_mfma_f32_16x16x32_bf16(af[i], bfr[j], acc[i][j], 0, 0, 0);
    }

    const int col = lane & 15, rbase = (lane >> 4) * 4;
#pragma unroll
    for (int j = 0; j < 4; j++) {
        const int n = n0 + wn + j * 16 + col;
        const float bv = bias ? bias[n] : 0.0f;
#pragma unroll
        for (int i = 0; i < 4; i++) {
#pragma unroll
            for (int r = 0; r < 4; r++) {
                const int m = m0 + wm + i * 16 + rbase + r;
                Cb[(size_t)m * N + n] = acc[i][j][r] + bv;
            }
        }
    }
}

// ---------------------------------------------------------------------------
// k-row stats: per k-row (4096 rows) compute (max, 1/sumexp). grid 4096.
// ---------------------------------------------------------------------------
__global__ __launch_bounds__(256) void kstats(const float* __restrict__ qkv,
                                              float2* __restrict__ stats) {
    const int r = blockIdx.x;
    const int b = r >> 9, hc = r & 511;
    const float* row = qkv + (size_t)b * 1536 * L + (size_t)(512 + hc) * L;
    __shared__ float sred[4];
    const int t = threadIdx.x;
    float v[16];
    float m = -1e30f;
#pragma unroll
    for (int i = 0; i < 16; i++) {
        v[i] = row[t + 256 * i];
        m = fmaxf(m, v[i]);
    }
#pragma unroll
    for (int off = 32; off > 0; off >>= 1) m = fmaxf(m, __shfl_down(m, off, 64));
    if ((t & 63) == 0) sred[t >> 6] = m;
    __syncthreads();
    const float m4 = fmaxf(fmaxf(sred[0], sred[1]), fmaxf(sred[2], sred[3]));
    float s = 0.f;
#pragma unroll
    for (int i = 0; i < 16; i++) s += __expf(v[i] - m4);
#pragma unroll
    for (int off = 32; off > 0; off >>= 1) s += __shfl_down(s, off, 64);
    __syncthreads();
    if ((t & 63) == 0) sred[t >> 6] = s;
    __syncthreads();
    if (t == 0) {
        const float stot = sred[0] + sred[1] + sred[2] + sred[3];
        stats[r] = make_float2(m4, 1.0f / stot);
    }
}

// ---------------------------------------------------------------------------
// context partials with fused k-softmax:
// ctx[chunk][bh][d][e] = (1/s_d) * sum_{n in chunk} exp(k[d,n]-m_d) * v[e,n]
// ---------------------------------------------------------------------------
__global__ __launch_bounds__(256) void context_partial(const float* __restrict__ qkv,
                                                       const float2* __restrict__ stats,
                                                       float* __restrict__ ctx) {
    const int chunk = blockIdx.x;
    const int bh = blockIdx.y;
    const int b = bh >> 3, h = bh & 7;
    const float* kbase = qkv + (size_t)b * 1536 * L + (size_t)(512 + h * 64) * L;
    const float* vbase = qkv + (size_t)b * 1536 * L + (size_t)(1024 + h * 64) * L;
    __shared__ float sk[64][65];
    __shared__ float sv[64][65];
    __shared__ float smax[64];
    const int t = threadIdx.x;
    if (t < 64) smax[t] = stats[bh * 64 + t].x;
    const int tx = t % 16, ty = t / 16;
    float acc[4][4] = {};
    const int n_start = chunk * (L / NCH);
    __syncthreads();
    for (int ns = 0; ns < L / NCH; ns += 64) {
        const int n0 = n_start + ns;
        const int nn = t % 64, d0 = t / 64;
#pragma unroll
        for (int r = 0; r < 16; r++) {
            int d = d0 + r * 4;
            sk[d][nn] = __expf(kbase[(size_t)d * L + n0 + nn] - smax[d]);
            sv[d][nn] = vbase[(size_t)d * L + n0 + nn];
        }
        __syncthreads();
#pragma unroll 8
        for (int q = 0; q < 64; q++) {
            float a[4], bb[4];
#pragma unroll
            for (int i = 0; i < 4; i++) a[i] = sk[ty * 4 + i][q];
#pragma unroll
            for (int j = 0; j < 4; j++) bb[j] = sv[tx * 4 + j][q];
#pragma unroll
            for (int i = 0; i < 4; i++)
#pragma unroll
                for (int j = 0; j < 4; j++) acc[i][j] += a[i] * bb[j];
        }
        __syncthreads();
    }
    float invs[4];
#pragma unroll
    for (int i = 0; i < 4; i++) invs[i] = stats[bh * 64 + ty * 4 + i].y;
    float* cp = ctx + ((size_t)chunk * 64 + bh) * 4096;
#pragma unroll
    for (int i = 0; i < 4; i++) {
        float4 v = make_float4(acc[i][0] * invs[i], acc[i][1] * invs[i],
                               acc[i][2] * invs[i], acc[i][3] * invs[i]);
        *(float4*)(cp + (ty * 4 + i) * 64 + tx * 4) = v;
    }
}

// ---------------------------------------------------------------------------
// pv with fused q-softmax: p_d = softmax_d(q[d,n]); outT[n][h*64+e] (bf16)
//   = sum_d ctx[d,e] * p_d.  Writes into dead k-region of qkv.
// ---------------------------------------------------------------------------
__global__ __launch_bounds__(256) void pv_kernel(float* __restrict__ qkv,
                                                 const float* __restrict__ ctx) {
    const int lc = blockIdx.x;
    const int bh = blockIdx.y;
    const int b = bh >> 3, h = bh & 7;
    __shared__ float sc[4096];
    const int t = threadIdx.x;
#pragma unroll
    for (int r = 0; r < 16; r++) {
        const int idx = t + r * 256;
        float s = 0.f;
        for (int ch = 0; ch < NCH; ch++)
            s += ctx[((size_t)ch * 64 + bh) * 4096 + idx];
        sc[idx] = s;
    }
    __syncthreads();
    const float* qbase = qkv + (size_t)b * 1536 * L + (size_t)(h * 64) * L;
    const int n = lc * 256 + t;
    float p[64];
    float m = -1e30f;
#pragma unroll
    for (int d = 0; d < 64; d++) {
        p[d] = qbase[(size_t)d * L + n];
        m = fmaxf(m, p[d]);
    }
    float s = 0.f;
#pragma unroll
    for (int d = 0; d < 64; d++) {
        p[d] = __expf(p[d] - m);
        s += p[d];
    }
    const float inv = 1.0f / s;
#pragma unroll
    for (int d = 0; d < 64; d++) p[d] *= inv;

    __bf16* ob = (__bf16*)(qkv + (size_t)b * 1536 * L + (size_t)512 * L) + (size_t)n * 512 + h * 64;
#pragma unroll
    for (int half = 0; half < 2; half++) {
        float acc[32] = {};
#pragma unroll 4
        for (int d = 0; d < 64; d++) {
            const float pd = p[d];
#pragma unroll
            for (int e = 0; e < 32; e++) acc[e] += sc[d * 64 + half * 32 + e] * pd;
        }
#pragma unroll
        for (int e0 = 0; e0 < 32; e0 += 8) {
            bf16x8 pk;
#pragma unroll
            for (int j = 0; j < 8; j++) pk[j] = (__bf16)acc[e0 + j];
            *(bf16x8*)(ob + half * 32 + e0) = pk;
        }
    }
}

// ---------------------------------------------------------------------------
extern "C" void kernel_launch(void* const* d_in, const int* in_sizes, int n_in,
                              void* d_out, int out_size, void* d_ws, size_t ws_size,
                              hipStream_t stream) {
    const float* x    = (const float*)d_in[0];
    const float* Wqkv = (const float*)d_in[1];
    const float* Wout = (const float*)d_in[2];
    const float* bout = (const float*)d_in[3];
    float* y = (float*)d_out;

    float*  qkv   = (float*)d_ws;                                // 8*1536*4096 f32
    float*  ctx   = qkv + (size_t)8 * 1536 * L;                  // NCH*64*4096 f32
    __bf16* xb    = (__bf16*)(ctx + (size_t)NCH * 64 * 4096);    // 8*4096*512 bf16
    __bf16* Wqb   = xb + (size_t)8 * 4096 * 512;                 // 1536*512 bf16
    __bf16* Wob   = Wqb + (size_t)1536 * 512;                    // 512*512 bf16
    float2* stats = (float2*)(Wob + (size_t)512 * 512);          // 4096 float2

    f32_to_bf16<<<dim3((8 * 4096 * 512 / 8 + 255) / 256), 256, 0, stream>>>(x, xb, 8 * 4096 * 512 / 8);
    f32_to_bf16<<<dim3((1536 * 512 / 8 + 255) / 256), 256, 0, stream>>>(Wqkv, Wqb, 1536 * 512 / 8);
    f32_to_bf16<<<dim3((512 * 512 / 8 + 255) / 256), 256, 0, stream>>>(Wout, Wob, 512 * 512 / 8);

    // qkv[b][o][l] = sum_d Wqkv[o][d] * x[b][l][d]   (M=1536, N=4096, K=512)
    gemm_bf16_mfma<1536, 4096, 512><<<dim3(4096 / 128, 1536 / 128, 8), 256, 0, stream>>>(
        Wqb, 0, xb, (size_t)4096 * 512, qkv, (size_t)1536 * 4096, nullptr);

    kstats<<<dim3(4096), 256, 0, stream>>>(qkv, stats);
    context_partial<<<dim3(NCH, 64), 256, 0, stream>>>(qkv, stats, ctx);
    pv_kernel<<<dim3(L / 256, 64), 256, 0, stream>>>(qkv, ctx);

    // y[b][l][d] = sum_c outT[b][l][c] * Wout[d][c] + bout[d]  (M=4096, N=512, K=512)
    const __bf16* outT = (const __bf16*)(qkv + (size_t)512 * L);
    gemm_bf16_mfma<4096, 512, 512><<<dim3(512 / 128, 4096 / 128, 8), 256, 0, stream>>>(
        outT, (size_t)1536 * L * 2, Wob, 0, y, (size_t)4096 * 512, bout);
}

// Round 4
// 324.391 us; speedup vs baseline: 1.3606x; 1.3606x over previous
//
#include <hip/hip_runtime.h>

#define L 4096
#define D 512
#define NCH 16   // context n-chunks

typedef __bf16 bf16x8 __attribute__((ext_vector_type(8)));
typedef float  f32x4  __attribute__((ext_vector_type(4)));

__device__ __forceinline__ void load_lds16(const void* g, void* l) {
    __builtin_amdgcn_global_load_lds(
        (const __attribute__((address_space(1))) void*)g,
        (__attribute__((address_space(3))) void*)l, 16, 0, 0);
}

// ---------------------------------------------------------------------------
// f32 -> bf16 conversion (8 elems / thread, 16B stores)
// ---------------------------------------------------------------------------
__global__ __launch_bounds__(256) void f32_to_bf16(const float* __restrict__ in,
                                                   __bf16* __restrict__ out, int n8) {
    int i = blockIdx.x * 256 + threadIdx.x;
    if (i >= n8) return;
    const float4* p = (const float4*)in + (size_t)i * 2;
    float4 a = p[0], b = p[1];
    bf16x8 o = {(__bf16)a.x, (__bf16)a.y, (__bf16)a.z, (__bf16)a.w,
                (__bf16)b.x, (__bf16)b.y, (__bf16)b.z, (__bf16)b.w};
    *(bf16x8*)(out + (size_t)i * 8) = o;
}

// ---------------------------------------------------------------------------
// Generic TN bf16 MFMA GEMM: C[b][m][n] = sum_k A[b][m][k] * B[b][n][k] (+bias[n])
// 128x128 tile, BK=32, 4 waves. XOR-swizzled LDS staging.
// ---------------------------------------------------------------------------
template <int M, int N, int K>
__global__ __launch_bounds__(256) void gemm_bf16_mfma(
    const __bf16* __restrict__ A, size_t aStride,
    const __bf16* __restrict__ B, size_t bStride,
    float* __restrict__ C, size_t cStride,
    const float* __restrict__ bias) {
    __shared__ __align__(16) __bf16 sA[128 * 32];
    __shared__ __align__(16) __bf16 sB[128 * 32];
    const int b  = blockIdx.z;
    const int m0 = blockIdx.y * 128;
    const int n0 = blockIdx.x * 128;
    const int t    = threadIdx.x;
    const int wave = t >> 6, lane = t & 63;
    const int wm = (wave & 1) * 64, wn = (wave >> 1) * 64;
    const __bf16* Ab = A + (size_t)b * aStride;
    const __bf16* Bb = B + (size_t)b * bStride;
    float* Cb = C + (size_t)b * cStride;

    f32x4 acc[4][4];
#pragma unroll
    for (int i = 0; i < 4; i++)
#pragma unroll
        for (int j = 0; j < 4; j++) acc[i][j] = (f32x4)(0.0f);

    const int fr = lane & 15;            // m (A) / n (B) within 16-tile
    const int cq = lane >> 4;            // k-chunk 0..3 wanted by this lane
    const int ko = (cq ^ ((fr >> 1) & 3)) * 8;  // swizzled LDS k-offset

    for (int k0 = 0; k0 < K; k0 += 32) {
        __syncthreads();
#pragma unroll
        for (int c = 0; c < 2; c++) {
            const int idx = c * 256 + t;
            const int row = idx >> 2, cc = idx & 3;
            const int scc = cc ^ ((row >> 1) & 3);   // source chunk for this slot
            load_lds16(Ab + (size_t)(m0 + row) * K + k0 + scc * 8, &sA[idx * 8]);
            load_lds16(Bb + (size_t)(n0 + row) * K + k0 + scc * 8, &sB[idx * 8]);
        }
        __syncthreads();
        bf16x8 af[4], bfr[4];
#pragma unroll
        for (int i = 0; i < 4; i++) {
            af[i]  = *(const bf16x8*)&sA[(wm + i * 16 + fr) * 32 + ko];
            bfr[i] = *(const bf16x8*)&sB[(wn + i * 16 + fr) * 32 + ko];
        }
#pragma unroll
        for (int i = 0; i < 4; i++)
#pragma unroll
            for (int j = 0; j < 4; j++)
                acc[i][j] = __builtin_amdgcn_mfma_f32_16x16x32_bf16(af[i], bfr[j], acc[i][j], 0, 0, 0);
    }

    const int col = lane & 15, rbase = (lane >> 4) * 4;
#pragma unroll
    for (int j = 0; j < 4; j++) {
        const int n = n0 + wn + j * 16 + col;
        const float bv = bias ? bias[n] : 0.0f;
#pragma unroll
        for (int i = 0; i < 4; i++) {
#pragma unroll
            for (int r = 0; r < 4; r++) {
                const int m = m0 + wm + i * 16 + rbase + r;
                Cb[(size_t)m * N + n] = acc[i][j][r] + bv;
            }
        }
    }
}

// ---------------------------------------------------------------------------
// k-row stats: per k-row (4096 rows) compute (max, 1/sumexp). grid 4096.
// ---------------------------------------------------------------------------
__global__ __launch_bounds__(256) void kstats(const float* __restrict__ qkv,
                                              float2* __restrict__ stats) {
    const int r = blockIdx.x;
    const int b = r >> 9, hc = r & 511;
    const float* row = qkv + (size_t)b * 1536 * L + (size_t)(512 + hc) * L;
    __shared__ float sred[4];
    const int t = threadIdx.x;
    float v[16];
    float m = -1e30f;
#pragma unroll
    for (int i = 0; i < 16; i++) {
        v[i] = row[t + 256 * i];
        m = fmaxf(m, v[i]);
    }
#pragma unroll
    for (int off = 32; off > 0; off >>= 1) m = fmaxf(m, __shfl_down(m, off, 64));
    if ((t & 63) == 0) sred[t >> 6] = m;
    __syncthreads();
    const float m4 = fmaxf(fmaxf(sred[0], sred[1]), fmaxf(sred[2], sred[3]));
    float s = 0.f;
#pragma unroll
    for (int i = 0; i < 16; i++) s += __expf(v[i] - m4);
#pragma unroll
    for (int off = 32; off > 0; off >>= 1) s += __shfl_down(s, off, 64);
    __syncthreads();
    if ((t & 63) == 0) sred[t >> 6] = s;
    __syncthreads();
    if (t == 0) {
        const float stot = sred[0] + sred[1] + sred[2] + sred[3];
        stats[r] = make_float2(m4, 1.0f / stot);
    }
}

// ---------------------------------------------------------------------------
// context partials with fused k-softmax, TRANSPOSED output [e][d]:
// ctx[chunk][bh][e][d] = (1/s_d) * sum_{n in chunk} exp(k[d,n]-m_d) * v[e,n]
// ---------------------------------------------------------------------------
__global__ __launch_bounds__(256) void context_partial(const float* __restrict__ qkv,
                                                       const float2* __restrict__ stats,
                                                       float* __restrict__ ctx) {
    const int chunk = blockIdx.x;
    const int bh = blockIdx.y;
    const int b = bh >> 3, h = bh & 7;
    const float* kbase = qkv + (size_t)b * 1536 * L + (size_t)(512 + h * 64) * L;
    const float* vbase = qkv + (size_t)b * 1536 * L + (size_t)(1024 + h * 64) * L;
    __shared__ float sk[64][65];
    __shared__ float sv[64][65];
    __shared__ float smax[64];
    const int t = threadIdx.x;
    if (t < 64) smax[t] = stats[bh * 64 + t].x;
    const int tx = t % 16, ty = t / 16;
    float acc[4][4] = {};  // acc[i=d][j=e]
    const int n_start = chunk * (L / NCH);
    __syncthreads();
    for (int ns = 0; ns < L / NCH; ns += 64) {
        const int n0 = n_start + ns;
        const int nn = t % 64, d0 = t / 64;
#pragma unroll
        for (int r = 0; r < 16; r++) {
            int d = d0 + r * 4;
            sk[d][nn] = __expf(kbase[(size_t)d * L + n0 + nn] - smax[d]);
            sv[d][nn] = vbase[(size_t)d * L + n0 + nn];
        }
        __syncthreads();
#pragma unroll 8
        for (int q = 0; q < 64; q++) {
            float a[4], bb[4];
#pragma unroll
            for (int i = 0; i < 4; i++) a[i] = sk[ty * 4 + i][q];
#pragma unroll
            for (int j = 0; j < 4; j++) bb[j] = sv[tx * 4 + j][q];
#pragma unroll
            for (int i = 0; i < 4; i++)
#pragma unroll
                for (int j = 0; j < 4; j++) acc[i][j] += a[i] * bb[j];
        }
        __syncthreads();
    }
    float invs[4];
#pragma unroll
    for (int i = 0; i < 4; i++) invs[i] = stats[bh * 64 + ty * 4 + i].y;
    float* cp = ctx + ((size_t)chunk * 64 + bh) * 4096;
    // transposed write: element (e = tx*4+j, d = ty*4+i)
#pragma unroll
    for (int j = 0; j < 4; j++) {
        float4 v = make_float4(acc[0][j] * invs[0], acc[1][j] * invs[1],
                               acc[2][j] * invs[2], acc[3][j] * invs[3]);
        *(float4*)(cp + (tx * 4 + j) * 64 + ty * 4) = v;
    }
}

// ---------------------------------------------------------------------------
// reduce ctx partials over chunks -> bf16 ctxT[bh][e][d]. grid 64.
// ---------------------------------------------------------------------------
__global__ __launch_bounds__(256) void ctx_reduce(const float* __restrict__ ctx,
                                                  __bf16* __restrict__ ctxT) {
    const int bh = blockIdx.x;
    const int t = threadIdx.x;
#pragma unroll
    for (int r = 0; r < 16; r++) {
        const int idx = t + r * 256;
        float s = 0.f;
        for (int ch = 0; ch < NCH; ch++)
            s += ctx[((size_t)ch * 64 + bh) * 4096 + idx];
        ctxT[(size_t)bh * 4096 + idx] = (__bf16)s;
    }
}

// ---------------------------------------------------------------------------
// pv_fused: per (bh, 256-col tile): q-softmax (unnormalized exp in LDS bf16)
// + MFMA 256x64 K=64 against ctxT, normalize in epilogue, write bf16 outT.
// ---------------------------------------------------------------------------
#define SPS 66   // LDS row stride (bf16): 33 dwords -> conflict-free writes
__global__ __launch_bounds__(256) void pv_fused(float* __restrict__ qkv,
                                                const __bf16* __restrict__ ctxT) {
    __shared__ __align__(16) __bf16 sp[256 * SPS];   // p rows [n][d]
    __shared__ __align__(16) __bf16 sctx[64 * SPS];  // ctxT rows [e][d]
    __shared__ float sinv[256];
    const int tileN = blockIdx.x;
    const int bh = blockIdx.y;
    const int b = bh >> 3, h = bh & 7;
    const int t = threadIdx.x;
    const int n0 = tileN * 256;
    const float* qbase = qkv + (size_t)b * 1536 * L + (size_t)(h * 64) * L;

    {   // stage ctxT (64x64 bf16): thread t -> row e=t/4, 16 bf16 at chunk (t&3)
        const int e = t >> 2, c = t & 3;
        const bf16x8* src = (const bf16x8*)(ctxT + ((size_t)bh * 64 + e) * 64 + c * 16);
        *(bf16x8*)&sctx[e * SPS + c * 16] = src[0];
        *(bf16x8*)&sctx[e * SPS + c * 16 + 8] = src[1];
    }

    // pass 1: read q column (coalesced across lanes), track max, stage bf16(q)
    float m = -1e30f;
#pragma unroll
    for (int d0 = 0; d0 < 64; d0 += 8) {
        bf16x8 pk;
#pragma unroll
        for (int j = 0; j < 8; j++) {
            float v = qbase[(size_t)(d0 + j) * L + n0 + t];
            m = fmaxf(m, v);
            pk[j] = (__bf16)v;
        }
        *(bf16x8*)&sp[t * SPS + d0] = pk;
    }
    // pass 2: exp from bf16 q (own row only), sum, store unnormalized exp
    float s = 0.f;
#pragma unroll
    for (int d0 = 0; d0 < 64; d0 += 8) {
        bf16x8 pk = *(bf16x8*)&sp[t * SPS + d0];
        bf16x8 ek;
#pragma unroll
        for (int j = 0; j < 8; j++) {
            float e = __expf((float)pk[j] - m);
            s += e;
            ek[j] = (__bf16)e;
        }
        *(bf16x8*)&sp[t * SPS + d0] = ek;
    }
    sinv[t] = 1.0f / s;
    __syncthreads();

    // MFMA: out[n][e] = sum_d p[n][d] * ctxT[e][d]; 4 waves x 64 rows
    const int wave = t >> 6, lane = t & 63;
    const int wm = wave * 64;
    const int fr = lane & 15, kq = (lane >> 4) * 8;
    f32x4 acc[4][4];
#pragma unroll
    for (int i = 0; i < 4; i++)
#pragma unroll
        for (int j = 0; j < 4; j++) acc[i][j] = (f32x4)(0.0f);
#pragma unroll
    for (int kh = 0; kh < 2; kh++) {
        bf16x8 af[4], bfr[4];
#pragma unroll
        for (int i = 0; i < 4; i++)
            af[i] = *(const bf16x8*)&sp[(wm + i * 16 + fr) * SPS + kh * 32 + kq];
#pragma unroll
        for (int j = 0; j < 4; j++)
            bfr[j] = *(const bf16x8*)&sctx[(j * 16 + fr) * SPS + kh * 32 + kq];
#pragma unroll
        for (int i = 0; i < 4; i++)
#pragma unroll
            for (int j = 0; j < 4; j++)
                acc[i][j] = __builtin_amdgcn_mfma_f32_16x16x32_bf16(af[i], bfr[j], acc[i][j], 0, 0, 0);
    }

    // epilogue: normalize by 1/s[n], write bf16 outT[b][n][h*64+e]
    __bf16* ob = (__bf16*)(qkv + (size_t)b * 1536 * L + (size_t)512 * L);
    const int col = lane & 15, rbase = (lane >> 4) * 4;
#pragma unroll
    for (int i = 0; i < 4; i++) {
#pragma unroll
        for (int r = 0; r < 4; r++) {
            const int nl = wm + i * 16 + rbase + r;
            const float inv = sinv[nl];
            const size_t rowoff = (size_t)(n0 + nl) * 512 + h * 64;
#pragma unroll
            for (int j = 0; j < 4; j++)
                ob[rowoff + j * 16 + col] = (__bf16)(acc[i][j][r] * inv);
        }
    }
}

// ---------------------------------------------------------------------------
extern "C" void kernel_launch(void* const* d_in, const int* in_sizes, int n_in,
                              void* d_out, int out_size, void* d_ws, size_t ws_size,
                              hipStream_t stream) {
    const float* x    = (const float*)d_in[0];
    const float* Wqkv = (const float*)d_in[1];
    const float* Wout = (const float*)d_in[2];
    const float* bout = (const float*)d_in[3];
    float* y = (float*)d_out;

    float*  qkv   = (float*)d_ws;                                // 8*1536*4096 f32
    float*  ctx   = qkv + (size_t)8 * 1536 * L;                  // NCH*64*4096 f32
    __bf16* xb    = (__bf16*)(ctx + (size_t)NCH * 64 * 4096);    // 8*4096*512 bf16
    __bf16* Wqb   = xb + (size_t)8 * 4096 * 512;                 // 1536*512 bf16
    __bf16* Wob   = Wqb + (size_t)1536 * 512;                    // 512*512 bf16
    float2* stats = (float2*)(Wob + (size_t)512 * 512);          // 4096 float2
    __bf16* ctxT  = (__bf16*)(stats + 4096);                     // 64*4096 bf16

    f32_to_bf16<<<dim3((8 * 4096 * 512 / 8 + 255) / 256), 256, 0, stream>>>(x, xb, 8 * 4096 * 512 / 8);
    f32_to_bf16<<<dim3((1536 * 512 / 8 + 255) / 256), 256, 0, stream>>>(Wqkv, Wqb, 1536 * 512 / 8);
    f32_to_bf16<<<dim3((512 * 512 / 8 + 255) / 256), 256, 0, stream>>>(Wout, Wob, 512 * 512 / 8);

    // qkv[b][o][l] = sum_d Wqkv[o][d] * x[b][l][d]   (M=1536, N=4096, K=512)
    gemm_bf16_mfma<1536, 4096, 512><<<dim3(4096 / 128, 1536 / 128, 8), 256, 0, stream>>>(
        Wqb, 0, xb, (size_t)4096 * 512, qkv, (size_t)1536 * 4096, nullptr);

    kstats<<<dim3(4096), 256, 0, stream>>>(qkv, stats);
    context_partial<<<dim3(NCH, 64), 256, 0, stream>>>(qkv, stats, ctx);
    ctx_reduce<<<dim3(64), 256, 0, stream>>>(ctx, ctxT);
    pv_fused<<<dim3(L / 256, 64), 256, 0, stream>>>(qkv, ctxT);

    // y[b][l][d] = sum_c outT[b][l][c] * Wout[d][c] + bout[d]  (M=4096, N=512, K=512)
    const __bf16* outT = (const __bf16*)(qkv + (size_t)512 * L);
    gemm_bf16_mfma<4096, 512, 512><<<dim3(512 / 128, 4096 / 128, 8), 256, 0, stream>>>(
        outT, (size_t)1536 * L * 2, Wob, 0, y, (size_t)4096 * 512, bout);
}

// Round 5
// 311.292 us; speedup vs baseline: 1.4178x; 1.0421x over previous
//
#include <hip/hip_runtime.h>

#define L 4096
#define D 512
#define NCH 16   // context n-chunks

typedef __bf16 bf16x8 __attribute__((ext_vector_type(8)));
typedef float  f32x4  __attribute__((ext_vector_type(4)));

__device__ __forceinline__ void load_lds16(const void* g, void* l) {
    __builtin_amdgcn_global_load_lds(
        (const __attribute__((address_space(1))) void*)g,
        (__attribute__((address_space(3))) void*)l, 16, 0, 0);
}

// ---------------------------------------------------------------------------
// f32 -> bf16 conversion (8 elems / thread, 16B stores)
// ---------------------------------------------------------------------------
__global__ __launch_bounds__(256) void f32_to_bf16(const float* __restrict__ in,
                                                   __bf16* __restrict__ out, int n8) {
    int i = blockIdx.x * 256 + threadIdx.x;
    if (i >= n8) return;
    const float4* p = (const float4*)in + (size_t)i * 2;
    float4 a = p[0], b = p[1];
    bf16x8 o = {(__bf16)a.x, (__bf16)a.y, (__bf16)a.z, (__bf16)a.w,
                (__bf16)b.x, (__bf16)b.y, (__bf16)b.z, (__bf16)b.w};
    *(bf16x8*)(out + (size_t)i * 8) = o;
}

// ---------------------------------------------------------------------------
// Generic TN bf16 MFMA GEMM: C[b][m][n] = sum_k A[b][m][k] * B[b][n][k] (+bias[n])
// 128x128 tile, BK=32, 4 waves, XOR-swizzled LDS. CT = float or __bf16 output.
// ---------------------------------------------------------------------------
template <int M, int N, int K, typename CT>
__global__ __launch_bounds__(256) void gemm_bf16_mfma(
    const __bf16* __restrict__ A, size_t aStride,
    const __bf16* __restrict__ B, size_t bStride,
    CT* __restrict__ C, size_t cStride,
    const float* __restrict__ bias) {
    __shared__ __align__(16) __bf16 sA[128 * 32];
    __shared__ __align__(16) __bf16 sB[128 * 32];
    const int b  = blockIdx.z;
    const int m0 = blockIdx.y * 128;
    const int n0 = blockIdx.x * 128;
    const int t    = threadIdx.x;
    const int wave = t >> 6, lane = t & 63;
    const int wm = (wave & 1) * 64, wn = (wave >> 1) * 64;
    const __bf16* Ab = A + (size_t)b * aStride;
    const __bf16* Bb = B + (size_t)b * bStride;
    CT* Cb = C + (size_t)b * cStride;

    f32x4 acc[4][4];
#pragma unroll
    for (int i = 0; i < 4; i++)
#pragma unroll
        for (int j = 0; j < 4; j++) acc[i][j] = (f32x4)(0.0f);

    const int fr = lane & 15;            // m (A) / n (B) within 16-tile
    const int cq = lane >> 4;            // k-chunk 0..3 wanted by this lane
    const int ko = (cq ^ ((fr >> 1) & 3)) * 8;  // swizzled LDS k-offset

    for (int k0 = 0; k0 < K; k0 += 32) {
        __syncthreads();
#pragma unroll
        for (int c = 0; c < 2; c++) {
            const int idx = c * 256 + t;
            const int row = idx >> 2, cc = idx & 3;
            const int scc = cc ^ ((row >> 1) & 3);   // source chunk for this slot
            load_lds16(Ab + (size_t)(m0 + row) * K + k0 + scc * 8, &sA[idx * 8]);
            load_lds16(Bb + (size_t)(n0 + row) * K + k0 + scc * 8, &sB[idx * 8]);
        }
        __syncthreads();
        bf16x8 af[4], bfr[4];
#pragma unroll
        for (int i = 0; i < 4; i++) {
            af[i]  = *(const bf16x8*)&sA[(wm + i * 16 + fr) * 32 + ko];
            bfr[i] = *(const bf16x8*)&sB[(wn + i * 16 + fr) * 32 + ko];
        }
#pragma unroll
        for (int i = 0; i < 4; i++)
#pragma unroll
            for (int j = 0; j < 4; j++)
                acc[i][j] = __builtin_amdgcn_mfma_f32_16x16x32_bf16(af[i], bfr[j], acc[i][j], 0, 0, 0);
    }

    const int col = lane & 15, rbase = (lane >> 4) * 4;
#pragma unroll
    for (int j = 0; j < 4; j++) {
        const int n = n0 + wn + j * 16 + col;
        const float bv = bias ? bias[n] : 0.0f;
#pragma unroll
        for (int i = 0; i < 4; i++) {
#pragma unroll
            for (int r = 0; r < 4; r++) {
                const int m = m0 + wm + i * 16 + rbase + r;
                Cb[(size_t)m * N + n] = (CT)(acc[i][j][r] + bv);
            }
        }
    }
}

// ---------------------------------------------------------------------------
// k-row stats over bf16 k rows: per row compute (max, 1/sumexp). grid 4096.
// ---------------------------------------------------------------------------
__global__ __launch_bounds__(256) void kstats(const __bf16* __restrict__ qkv,
                                              float2* __restrict__ stats) {
    const int r = blockIdx.x;
    const int b = r >> 9, hc = r & 511;
    const __bf16* row = qkv + (size_t)b * 1536 * L + (size_t)(512 + hc) * L;
    __shared__ float sred[4];
    const int t = threadIdx.x;
    const bf16x8* p = (const bf16x8*)row;
    bf16x8 c0 = p[t * 2], c1 = p[t * 2 + 1];
    float v[16];
    float m = -1e30f;
#pragma unroll
    for (int j = 0; j < 8; j++) {
        v[j] = (float)c0[j];
        v[8 + j] = (float)c1[j];
    }
#pragma unroll
    for (int j = 0; j < 16; j++) m = fmaxf(m, v[j]);
#pragma unroll
    for (int off = 32; off > 0; off >>= 1) m = fmaxf(m, __shfl_down(m, off, 64));
    if ((t & 63) == 0) sred[t >> 6] = m;
    __syncthreads();
    const float m4 = fmaxf(fmaxf(sred[0], sred[1]), fmaxf(sred[2], sred[3]));
    float s = 0.f;
#pragma unroll
    for (int j = 0; j < 16; j++) s += __expf(v[j] - m4);
#pragma unroll
    for (int off = 32; off > 0; off >>= 1) s += __shfl_down(s, off, 64);
    __syncthreads();
    if ((t & 63) == 0) sred[t >> 6] = s;
    __syncthreads();
    if (t == 0) {
        const float stot = sred[0] + sred[1] + sred[2] + sred[3];
        stats[r] = make_float2(m4, 1.0f / stot);
    }
}

// ---------------------------------------------------------------------------
// context partials with fused k-softmax (bf16 in), TRANSPOSED output [e][d]:
// ctx[chunk][bh][e][d] = (1/s_d) * sum_{n in chunk} exp(k[d,n]-m_d) * v[e,n]
// ---------------------------------------------------------------------------
__global__ __launch_bounds__(256) void context_partial(const __bf16* __restrict__ qkv,
                                                       const float2* __restrict__ stats,
                                                       float* __restrict__ ctx) {
    const int chunk = blockIdx.x;
    const int bh = blockIdx.y;
    const int b = bh >> 3, h = bh & 7;
    const __bf16* kbase = qkv + (size_t)b * 1536 * L + (size_t)(512 + h * 64) * L;
    const __bf16* vbase = qkv + (size_t)b * 1536 * L + (size_t)(1024 + h * 64) * L;
    __shared__ float sk[64][65];
    __shared__ float sv[64][65];
    __shared__ float smax[64];
    const int t = threadIdx.x;
    if (t < 64) smax[t] = stats[bh * 64 + t].x;
    const int tx = t % 16, ty = t / 16;
    float acc[4][4] = {};  // acc[i=d][j=e]
    const int n_start = chunk * (L / NCH);
    __syncthreads();
    for (int ns = 0; ns < L / NCH; ns += 64) {
        const int n0 = n_start + ns;
        const int nn = t % 64, d0 = t / 64;
#pragma unroll
        for (int r = 0; r < 16; r++) {
            int d = d0 + r * 4;
            sk[d][nn] = __expf((float)kbase[(size_t)d * L + n0 + nn] - smax[d]);
            sv[d][nn] = (float)vbase[(size_t)d * L + n0 + nn];
        }
        __syncthreads();
#pragma unroll 8
        for (int q = 0; q < 64; q++) {
            float a[4], bb[4];
#pragma unroll
            for (int i = 0; i < 4; i++) a[i] = sk[ty * 4 + i][q];
#pragma unroll
            for (int j = 0; j < 4; j++) bb[j] = sv[tx * 4 + j][q];
#pragma unroll
            for (int i = 0; i < 4; i++)
#pragma unroll
                for (int j = 0; j < 4; j++) acc[i][j] += a[i] * bb[j];
        }
        __syncthreads();
    }
    float invs[4];
#pragma unroll
    for (int i = 0; i < 4; i++) invs[i] = stats[bh * 64 + ty * 4 + i].y;
    float* cp = ctx + ((size_t)chunk * 64 + bh) * 4096;
    // transposed write: element (e = tx*4+j, d = ty*4+i)
#pragma unroll
    for (int j = 0; j < 4; j++) {
        float4 v = make_float4(acc[0][j] * invs[0], acc[1][j] * invs[1],
                               acc[2][j] * invs[2], acc[3][j] * invs[3]);
        *(float4*)(cp + (tx * 4 + j) * 64 + ty * 4) = v;
    }
}

// ---------------------------------------------------------------------------
// reduce ctx partials over chunks -> bf16 ctxT[bh][e][d]. grid 256.
// ---------------------------------------------------------------------------
__global__ __launch_bounds__(256) void ctx_reduce(const float* __restrict__ ctx,
                                                  __bf16* __restrict__ ctxT) {
    const int bh = blockIdx.x >> 2, quarter = blockIdx.x & 3;
    const int t = threadIdx.x;
    const int idx = quarter * 1024 + t * 4;
    float4 s = make_float4(0.f, 0.f, 0.f, 0.f);
    for (int ch = 0; ch < NCH; ch++) {
        float4 p = *(const float4*)&ctx[((size_t)ch * 64 + bh) * 4096 + idx];
        s.x += p.x; s.y += p.y; s.z += p.z; s.w += p.w;
    }
    __bf16* o = ctxT + (size_t)bh * 4096 + idx;
    o[0] = (__bf16)s.x; o[1] = (__bf16)s.y; o[2] = (__bf16)s.z; o[3] = (__bf16)s.w;
}

// ---------------------------------------------------------------------------
// pv_fused: per (bh, 256-col tile): q-softmax (unnormalized exp in LDS bf16)
// + MFMA 256x64 K=64 against ctxT, normalize in epilogue, write bf16 outT.
// ---------------------------------------------------------------------------
#define SPS 66   // LDS row stride (bf16)
__global__ __launch_bounds__(256) void pv_fused(__bf16* __restrict__ qkv,
                                                const __bf16* __restrict__ ctxT) {
    __shared__ __align__(16) __bf16 sp[256 * SPS];   // p rows [n][d]
    __shared__ __align__(16) __bf16 sctx[64 * SPS];  // ctxT rows [e][d]
    __shared__ float sinv[256];
    const int tileN = blockIdx.x;
    const int bh = blockIdx.y;
    const int b = bh >> 3, h = bh & 7;
    const int t = threadIdx.x;
    const int n0 = tileN * 256;
    const __bf16* qbase = qkv + (size_t)b * 1536 * L + (size_t)(h * 64) * L;

    {   // stage ctxT (64x64 bf16)
        const int e = t >> 2, c = t & 3;
        const bf16x8* src = (const bf16x8*)(ctxT + ((size_t)bh * 64 + e) * 64 + c * 16);
        *(bf16x8*)&sctx[e * SPS + c * 16] = src[0];
        *(bf16x8*)&sctx[e * SPS + c * 16 + 8] = src[1];
    }

    // pass 1: read bf16 q column (coalesced across lanes), exp, sum, stage
    float m = -1e30f;
    float qv[64];
#pragma unroll
    for (int d = 0; d < 64; d++) {
        qv[d] = (float)qbase[(size_t)d * L + n0 + t];
        m = fmaxf(m, qv[d]);
    }
    float s = 0.f;
#pragma unroll
    for (int d0 = 0; d0 < 64; d0 += 8) {
        bf16x8 ek;
#pragma unroll
        for (int j = 0; j < 8; j++) {
            float e = __expf(qv[d0 + j] - m);
            s += e;
            ek[j] = (__bf16)e;
        }
        *(bf16x8*)&sp[t * SPS + d0] = ek;
    }
    sinv[t] = 1.0f / s;
    __syncthreads();

    // MFMA: out[n][e] = sum_d p[n][d] * ctxT[e][d]; 4 waves x 64 rows
    const int wave = t >> 6, lane = t & 63;
    const int wm = wave * 64;
    const int fr = lane & 15, kq = (lane >> 4) * 8;
    f32x4 acc[4][4];
#pragma unroll
    for (int i = 0; i < 4; i++)
#pragma unroll
        for (int j = 0; j < 4; j++) acc[i][j] = (f32x4)(0.0f);
#pragma unroll
    for (int kh = 0; kh < 2; kh++) {
        bf16x8 af[4], bfr[4];
#pragma unroll
        for (int i = 0; i < 4; i++)
            af[i] = *(const bf16x8*)&sp[(wm + i * 16 + fr) * SPS + kh * 32 + kq];
#pragma unroll
        for (int j = 0; j < 4; j++)
            bfr[j] = *(const bf16x8*)&sctx[(j * 16 + fr) * SPS + kh * 32 + kq];
#pragma unroll
        for (int i = 0; i < 4; i++)
#pragma unroll
            for (int j = 0; j < 4; j++)
                acc[i][j] = __builtin_amdgcn_mfma_f32_16x16x32_bf16(af[i], bfr[j], acc[i][j], 0, 0, 0);
    }

    // epilogue: normalize by 1/s[n], write bf16 outT[b][n][h*64+e]
    __bf16* ob = qkv + (size_t)b * 1536 * L + (size_t)512 * L;
    const int col = lane & 15, rbase = (lane >> 4) * 4;
#pragma unroll
    for (int i = 0; i < 4; i++) {
#pragma unroll
        for (int r = 0; r < 4; r++) {
            const int nl = wm + i * 16 + rbase + r;
            const float inv = sinv[nl];
            const size_t rowoff = (size_t)(n0 + nl) * 512 + h * 64;
#pragma unroll
            for (int j = 0; j < 4; j++)
                ob[rowoff + j * 16 + col] = (__bf16)(acc[i][j][r] * inv);
        }
    }
}

// ---------------------------------------------------------------------------
extern "C" void kernel_launch(void* const* d_in, const int* in_sizes, int n_in,
                              void* d_out, int out_size, void* d_ws, size_t ws_size,
                              hipStream_t stream) {
    const float* x    = (const float*)d_in[0];
    const float* Wqkv = (const float*)d_in[1];
    const float* Wout = (const float*)d_in[2];
    const float* bout = (const float*)d_in[3];
    float* y = (float*)d_out;

    __bf16* qkv   = (__bf16*)d_ws;                               // 8*1536*4096 bf16
    float*  ctx   = (float*)(qkv + (size_t)8 * 1536 * L);        // NCH*64*4096 f32
    __bf16* xb    = (__bf16*)(ctx + (size_t)NCH * 64 * 4096);    // 8*4096*512 bf16
    __bf16* Wqb   = xb + (size_t)8 * 4096 * 512;                 // 1536*512 bf16
    __bf16* Wob   = Wqb + (size_t)1536 * 512;                    // 512*512 bf16
    float2* stats = (float2*)(Wob + (size_t)512 * 512);          // 4096 float2
    __bf16* ctxT  = (__bf16*)(stats + 4096);                     // 64*4096 bf16

    f32_to_bf16<<<dim3((8 * 4096 * 512 / 8 + 255) / 256), 256, 0, stream>>>(x, xb, 8 * 4096 * 512 / 8);
    f32_to_bf16<<<dim3((1536 * 512 / 8 + 255) / 256), 256, 0, stream>>>(Wqkv, Wqb, 1536 * 512 / 8);
    f32_to_bf16<<<dim3((512 * 512 / 8 + 255) / 256), 256, 0, stream>>>(Wout, Wob, 512 * 512 / 8);

    // qkv[b][o][l] = sum_d Wqkv[o][d] * x[b][l][d]   (M=1536, N=4096, K=512), bf16 out
    gemm_bf16_mfma<1536, 4096, 512, __bf16><<<dim3(4096 / 128, 1536 / 128, 8), 256, 0, stream>>>(
        Wqb, 0, xb, (size_t)4096 * 512, qkv, (size_t)1536 * 4096, nullptr);

    kstats<<<dim3(4096), 256, 0, stream>>>(qkv, stats);
    context_partial<<<dim3(NCH, 64), 256, 0, stream>>>(qkv, stats, ctx);
    ctx_reduce<<<dim3(256), 256, 0, stream>>>(ctx, ctxT);
    pv_fused<<<dim3(L / 256, 64), 256, 0, stream>>>(qkv, ctxT);

    // y[b][l][d] = sum_c outT[b][l][c] * Wout[d][c] + bout[d]  (M=4096, N=512, K=512), f32 out
    const __bf16* outT = qkv + (size_t)512 * L;
    gemm_bf16_mfma<4096, 512, 512, float><<<dim3(512 / 128, 4096 / 128, 8), 256, 0, stream>>>(
        outT, (size_t)1536 * L, Wob, 0, y, (size_t)4096 * 512, bout);
}

// Round 6
// 284.787 us; speedup vs baseline: 1.5498x; 1.0931x over previous
//
#include <hip/hip_runtime.h>

#define L 4096
#define D 512
#define NCH 16   // context n-chunks (256 n per chunk)

typedef __bf16 bf16x8 __attribute__((ext_vector_type(8)));
typedef float  f32x4  __attribute__((ext_vector_type(4)));

__device__ __forceinline__ void load_lds16(const void* g, void* l) {
    __builtin_amdgcn_global_load_lds(
        (const __attribute__((address_space(1))) void*)g,
        (__attribute__((address_space(3))) void*)l, 16, 0, 0);
}

// ---------------------------------------------------------------------------
// merged f32 -> bf16 conversion for x, Wqkv, Wout (contiguous dst regions)
// ---------------------------------------------------------------------------
#define NX8  (8 * 4096 * 512 / 8)
#define NW18 (1536 * 512 / 8)
#define NW28 (512 * 512 / 8)
__global__ __launch_bounds__(256) void convert_all(const float* __restrict__ x,
                                                   const float* __restrict__ Wq,
                                                   const float* __restrict__ Wo,
                                                   __bf16* __restrict__ dst) {
    int i = blockIdx.x * 256 + threadIdx.x;
    if (i >= NX8 + NW18 + NW28) return;
    const float* s;
    if (i < NX8)             s = x  + (size_t)i * 8;
    else if (i < NX8 + NW18) s = Wq + (size_t)(i - NX8) * 8;
    else                     s = Wo + (size_t)(i - NX8 - NW18) * 8;
    float4 a = ((const float4*)s)[0], b = ((const float4*)s)[1];
    bf16x8 o = {(__bf16)a.x, (__bf16)a.y, (__bf16)a.z, (__bf16)a.w,
                (__bf16)b.x, (__bf16)b.y, (__bf16)b.z, (__bf16)b.w};
    *(bf16x8*)(dst + (size_t)i * 8) = o;
}

// ---------------------------------------------------------------------------
// Generic TN bf16 MFMA GEMM: C[b][m][n] = sum_k A[b][m][k] * B[b][n][k] (+bias[n])
// 128x128 tile, BK=64, 4 waves. XOR swizzle: LDS slot (row,cc) holds global
// chunk cc^(row&7); fragment read offset ko = (cq ^ (fr&7))*8.
// ---------------------------------------------------------------------------
template <int M, int N, int K, typename CT>
__global__ __launch_bounds__(256) void gemm_bf16_mfma(
    const __bf16* __restrict__ A, size_t aStride,
    const __bf16* __restrict__ B, size_t bStride,
    CT* __restrict__ C, size_t cStride,
    const float* __restrict__ bias) {
    __shared__ __align__(16) __bf16 sA[128 * 64];
    __shared__ __align__(16) __bf16 sB[128 * 64];
    const int b  = blockIdx.z;
    const int m0 = blockIdx.y * 128;
    const int n0 = blockIdx.x * 128;
    const int t    = threadIdx.x;
    const int wave = t >> 6, lane = t & 63;
    const int wm = (wave & 1) * 64, wn = (wave >> 1) * 64;
    const __bf16* Ab = A + (size_t)b * aStride;
    const __bf16* Bb = B + (size_t)b * bStride;
    CT* Cb = C + (size_t)b * cStride;

    f32x4 acc[4][4];
#pragma unroll
    for (int i = 0; i < 4; i++)
#pragma unroll
        for (int j = 0; j < 4; j++) acc[i][j] = (f32x4)(0.0f);

    const int fr = lane & 15;     // m (A) / n (B) within 16-tile
    const int g  = lane >> 4;     // quarter-wave: k-chunk group

    for (int k0 = 0; k0 < K; k0 += 64) {
        __syncthreads();
#pragma unroll
        for (int c = 0; c < 4; c++) {
            const int idx = c * 256 + t;           // 0..1023
            const int row = idx >> 3, cc = idx & 7;
            const int scc = cc ^ (row & 7);        // source chunk for this slot
            load_lds16(Ab + (size_t)(m0 + row) * K + k0 + scc * 8, &sA[idx * 8]);
            load_lds16(Bb + (size_t)(n0 + row) * K + k0 + scc * 8, &sB[idx * 8]);
        }
        __syncthreads();
#pragma unroll
        for (int kh = 0; kh < 2; kh++) {
            const int ko = ((kh * 4 + g) ^ (fr & 7)) * 8;
            bf16x8 af[4], bfr[4];
#pragma unroll
            for (int i = 0; i < 4; i++) {
                af[i]  = *(const bf16x8*)&sA[(wm + i * 16 + fr) * 64 + ko];
                bfr[i] = *(const bf16x8*)&sB[(wn + i * 16 + fr) * 64 + ko];
            }
#pragma unroll
            for (int i = 0; i < 4; i++)
#pragma unroll
                for (int j = 0; j < 4; j++)
                    acc[i][j] = __builtin_amdgcn_mfma_f32_16x16x32_bf16(af[i], bfr[j], acc[i][j], 0, 0, 0);
        }
    }

    const int col = lane & 15, rbase = g * 4;
#pragma unroll
    for (int j = 0; j < 4; j++) {
        const int n = n0 + wn + j * 16 + col;
        const float bv = bias ? bias[n] : 0.0f;
#pragma unroll
        for (int i = 0; i < 4; i++) {
#pragma unroll
            for (int r = 0; r < 4; r++) {
                const int m = m0 + wm + i * 16 + rbase + r;
                Cb[(size_t)m * N + n] = (CT)(acc[i][j][r] + bv);
            }
        }
    }
}

// ---------------------------------------------------------------------------
// k-row stats over bf16 k rows: per row compute (max, 1/sumexp). grid 4096.
// ---------------------------------------------------------------------------
__global__ __launch_bounds__(256) void kstats(const __bf16* __restrict__ qkv,
                                              float2* __restrict__ stats) {
    const int r = blockIdx.x;
    const int b = r >> 9, hc = r & 511;
    const __bf16* row = qkv + (size_t)b * 1536 * L + (size_t)(512 + hc) * L;
    __shared__ float sred[4];
    const int t = threadIdx.x;
    const bf16x8* p = (const bf16x8*)row;
    bf16x8 c0 = p[t * 2], c1 = p[t * 2 + 1];
    float v[16];
    float m = -1e30f;
#pragma unroll
    for (int j = 0; j < 8; j++) {
        v[j] = (float)c0[j];
        v[8 + j] = (float)c1[j];
    }
#pragma unroll
    for (int j = 0; j < 16; j++) m = fmaxf(m, v[j]);
#pragma unroll
    for (int off = 32; off > 0; off >>= 1) m = fmaxf(m, __shfl_down(m, off, 64));
    if ((t & 63) == 0) sred[t >> 6] = m;
    __syncthreads();
    const float m4 = fmaxf(fmaxf(sred[0], sred[1]), fmaxf(sred[2], sred[3]));
    float s = 0.f;
#pragma unroll
    for (int j = 0; j < 16; j++) s += __expf(v[j] - m4);
#pragma unroll
    for (int off = 32; off > 0; off >>= 1) s += __shfl_down(s, off, 64);
    __syncthreads();
    if ((t & 63) == 0) sred[t >> 6] = s;
    __syncthreads();
    if (t == 0) {
        const float stot = sred[0] + sred[1] + sred[2] + sred[3];
        stats[r] = make_float2(m4, 1.0f / stot);
    }
}

// ---------------------------------------------------------------------------
// MFMA context partials: ctxp[chunk][bh][d][e] (f32, d-major) =
//   sum_{n in chunk} exp(k[d,n]-m_d) * v[e,n]   (un-normalized; 1/s at reduce)
// grid (NCH, 64 bh), block 256. Each of 4 waves takes a 64-n K-slice.
// ---------------------------------------------------------------------------
#define SKS 264   // LDS bf16 row stride (256 data + 8 pad)
__global__ __launch_bounds__(256) void context_mfma(const __bf16* __restrict__ qkv,
                                                    const float2* __restrict__ stats,
                                                    float* __restrict__ ctxp) {
    __shared__ __align__(16) __bf16 smem[2 * 64 * SKS];  // 67.6 KB; reused as f32 red[4][4096]
    __shared__ float smax[64];
    __bf16* sk = smem;
    __bf16* sv = smem + 64 * SKS;
    const int chunk = blockIdx.x;
    const int bh = blockIdx.y;
    const int b = bh >> 3, h = bh & 7;
    const __bf16* kbase = qkv + (size_t)b * 1536 * L + (size_t)(512 + h * 64) * L;
    const __bf16* vbase = qkv + (size_t)b * 1536 * L + (size_t)(1024 + h * 64) * L;
    const int t = threadIdx.x;
    if (t < 64) smax[t] = stats[bh * 64 + t].x;
    __syncthreads();

    // stage: thread t -> row d = t>>2, n-quarter (t&3)*64
    {
        const int d = t >> 2, noff = (t & 3) * 64;
        const int n0 = chunk * 256;
        const __bf16* kp = kbase + (size_t)d * L + n0 + noff;
        const __bf16* vp = vbase + (size_t)d * L + n0 + noff;
        const float md = smax[d];
#pragma unroll
        for (int c = 0; c < 8; c++) {
            bf16x8 kk = *(const bf16x8*)(kp + c * 8);
            bf16x8 vv = *(const bf16x8*)(vp + c * 8);
            bf16x8 ek;
#pragma unroll
            for (int j = 0; j < 8; j++) ek[j] = (__bf16)__expf((float)kk[j] - md);
            *(bf16x8*)&sk[d * SKS + noff + c * 8] = ek;
            *(bf16x8*)&sv[d * SKS + noff + c * 8] = vv;
        }
    }
    __syncthreads();

    // MFMA: wave w covers n in [w*64, w*64+64)
    const int wave = t >> 6, lane = t & 63;
    const int fr = lane & 15, kq = (lane >> 4) * 8;
    f32x4 acc[4][4];
#pragma unroll
    for (int i = 0; i < 4; i++)
#pragma unroll
        for (int j = 0; j < 4; j++) acc[i][j] = (f32x4)(0.0f);
#pragma unroll
    for (int kh = 0; kh < 2; kh++) {
        const int koff = wave * 64 + kh * 32 + kq;
        bf16x8 af[4], bfr[4];
#pragma unroll
        for (int i = 0; i < 4; i++) {
            af[i]  = *(const bf16x8*)&sk[(i * 16 + fr) * SKS + koff];
            bfr[i] = *(const bf16x8*)&sv[(i * 16 + fr) * SKS + koff];
        }
#pragma unroll
        for (int i = 0; i < 4; i++)
#pragma unroll
            for (int j = 0; j < 4; j++)
                acc[i][j] = __builtin_amdgcn_mfma_f32_16x16x32_bf16(af[i], bfr[j], acc[i][j], 0, 0, 0);
    }
    __syncthreads();   // MFMA LDS reads done; safe to overwrite smem

    // cross-wave reduce via LDS: red[w][d*64+e] (d = A rows, e = B rows)
    float* red = (float*)smem;   // 4 * 4096 f32 = 64 KB
    const int col = lane & 15, rbase = (lane >> 4) * 4;
#pragma unroll
    for (int i = 0; i < 4; i++)
#pragma unroll
        for (int j = 0; j < 4; j++)
#pragma unroll
            for (int r = 0; r < 4; r++) {
                const int dd = i * 16 + rbase + r;
                const int ee = j * 16 + col;
                red[wave * 4096 + dd * 64 + ee] = acc[i][j][r];
            }
    __syncthreads();
    float* cp = ctxp + ((size_t)chunk * 64 + bh) * 4096;
#pragma unroll
    for (int gg = 0; gg < 4; gg++) {
        const int idx = t * 16 + gg * 4;
        f32x4 s = *(const f32x4*)&red[idx];
        s += *(const f32x4*)&red[4096 + idx];
        s += *(const f32x4*)&red[8192 + idx];
        s += *(const f32x4*)&red[12288 + idx];
        *(f32x4*)&cp[idx] = s;
    }
}

// ---------------------------------------------------------------------------
// reduce ctx partials over chunks, apply 1/s_d, transpose [d][e]->[e][d],
// emit bf16 ctxT[bh][e][d]. grid 256.
// ---------------------------------------------------------------------------
__global__ __launch_bounds__(256) void ctx_reduce(const float* __restrict__ ctxp,
                                                  const float2* __restrict__ stats,
                                                  __bf16* __restrict__ ctxT) {
    const int bh = blockIdx.x >> 2, quarter = blockIdx.x & 3;
    const int t = threadIdx.x;
    const int flat = quarter * 1024 + t * 4;   // d-major: d = flat>>6, e0 = flat&63
    const int d = flat >> 6, e0 = flat & 63;
    f32x4 s = (f32x4)(0.0f);
    for (int ch = 0; ch < NCH; ch++)
        s += *(const f32x4*)&ctxp[((size_t)ch * 64 + bh) * 4096 + flat];
    const float inv = stats[bh * 64 + d].y;
    __bf16* o = ctxT + (size_t)bh * 4096;
#pragma unroll
    for (int j = 0; j < 4; j++) o[(e0 + j) * 64 + d] = (__bf16)(s[j] * inv);
}

// ---------------------------------------------------------------------------
// pv_fused: per (bh, 256-col tile): q-softmax (unnormalized exp in LDS bf16)
// + MFMA 256x64 K=64 against ctxT, normalize in epilogue, write bf16 outT.
// ---------------------------------------------------------------------------
#define SPS 66   // LDS row stride (bf16)
__global__ __launch_bounds__(256) void pv_fused(__bf16* __restrict__ qkv,
                                                const __bf16* __restrict__ ctxT) {
    __shared__ __align__(16) __bf16 sp[256 * SPS];   // p rows [n][d]
    __shared__ __align__(16) __bf16 sctx[64 * SPS];  // ctxT rows [e][d]
    __shared__ float sinv[256];
    const int tileN = blockIdx.x;
    const int bh = blockIdx.y;
    const int b = bh >> 3, h = bh & 7;
    const int t = threadIdx.x;
    const int n0 = tileN * 256;
    const __bf16* qbase = qkv + (size_t)b * 1536 * L + (size_t)(h * 64) * L;

    {   // stage ctxT (64x64 bf16)
        const int e = t >> 2, c = t & 3;
        const bf16x8* src = (const bf16x8*)(ctxT + ((size_t)bh * 64 + e) * 64 + c * 16);
        *(bf16x8*)&sctx[e * SPS + c * 16] = src[0];
        *(bf16x8*)&sctx[e * SPS + c * 16 + 8] = src[1];
    }

    // read bf16 q column (coalesced across lanes), exp, sum, stage
    float m = -1e30f;
    float qv[64];
#pragma unroll
    for (int d = 0; d < 64; d++) {
        qv[d] = (float)qbase[(size_t)d * L + n0 + t];
        m = fmaxf(m, qv[d]);
    }
    float s = 0.f;
#pragma unroll
    for (int d0 = 0; d0 < 64; d0 += 8) {
        bf16x8 ek;
#pragma unroll
        for (int j = 0; j < 8; j++) {
            float e = __expf(qv[d0 + j] - m);
            s += e;
            ek[j] = (__bf16)e;
        }
        *(bf16x8*)&sp[t * SPS + d0] = ek;
    }
    sinv[t] = 1.0f / s;
    __syncthreads();

    // MFMA: out[n][e] = sum_d p[n][d] * ctxT[e][d]; 4 waves x 64 rows
    const int wave = t >> 6, lane = t & 63;
    const int wm = wave * 64;
    const int fr = lane & 15, kq = (lane >> 4) * 8;
    f32x4 acc[4][4];
#pragma unroll
    for (int i = 0; i < 4; i++)
#pragma unroll
        for (int j = 0; j < 4; j++) acc[i][j] = (f32x4)(0.0f);
#pragma unroll
    for (int kh = 0; kh < 2; kh++) {
        bf16x8 af[4], bfr[4];
#pragma unroll
        for (int i = 0; i < 4; i++)
            af[i] = *(const bf16x8*)&sp[(wm + i * 16 + fr) * SPS + kh * 32 + kq];
#pragma unroll
        for (int j = 0; j < 4; j++)
            bfr[j] = *(const bf16x8*)&sctx[(j * 16 + fr) * SPS + kh * 32 + kq];
#pragma unroll
        for (int i = 0; i < 4; i++)
#pragma unroll
            for (int j = 0; j < 4; j++)
                acc[i][j] = __builtin_amdgcn_mfma_f32_16x16x32_bf16(af[i], bfr[j], acc[i][j], 0, 0, 0);
    }

    // epilogue: normalize by 1/s[n], write bf16 outT[b][n][h*64+e]
    __bf16* ob = qkv + (size_t)b * 1536 * L + (size_t)512 * L;
    const int col = lane & 15, rbase = (lane >> 4) * 4;
#pragma unroll
    for (int i = 0; i < 4; i++) {
#pragma unroll
        for (int r = 0; r < 4; r++) {
            const int nl = wm + i * 16 + rbase + r;
            const float inv = sinv[nl];
            const size_t rowoff = (size_t)(n0 + nl) * 512 + h * 64;
#pragma unroll
            for (int j = 0; j < 4; j++)
                ob[rowoff + j * 16 + col] = (__bf16)(acc[i][j][r] * inv);
        }
    }
}

// ---------------------------------------------------------------------------
extern "C" void kernel_launch(void* const* d_in, const int* in_sizes, int n_in,
                              void* d_out, int out_size, void* d_ws, size_t ws_size,
                              hipStream_t stream) {
    const float* x    = (const float*)d_in[0];
    const float* Wqkv = (const float*)d_in[1];
    const float* Wout = (const float*)d_in[2];
    const float* bout = (const float*)d_in[3];
    float* y = (float*)d_out;

    __bf16* qkv   = (__bf16*)d_ws;                               // 8*1536*4096 bf16
    float*  ctxp  = (float*)(qkv + (size_t)8 * 1536 * L);        // NCH*64*4096 f32
    __bf16* xb    = (__bf16*)(ctxp + (size_t)NCH * 64 * 4096);   // 8*4096*512 bf16
    __bf16* Wqb   = xb + (size_t)8 * 4096 * 512;                 // 1536*512 bf16
    __bf16* Wob   = Wqb + (size_t)1536 * 512;                    // 512*512 bf16
    float2* stats = (float2*)(Wob + (size_t)512 * 512);          // 4096 float2
    __bf16* ctxT  = (__bf16*)(stats + 4096);                     // 64*4096 bf16

    const int convBlocks = (NX8 + NW18 + NW28 + 255) / 256;
    convert_all<<<dim3(convBlocks), 256, 0, stream>>>(x, Wqkv, Wout, xb);

    // qkv[b][o][l] = sum_d Wqkv[o][d] * x[b][l][d]   (M=1536, N=4096, K=512), bf16 out
    gemm_bf16_mfma<1536, 4096, 512, __bf16><<<dim3(4096 / 128, 1536 / 128, 8), 256, 0, stream>>>(
        Wqb, 0, xb, (size_t)4096 * 512, qkv, (size_t)1536 * 4096, nullptr);

    kstats<<<dim3(4096), 256, 0, stream>>>(qkv, stats);
    context_mfma<<<dim3(NCH, 64), 256, 0, stream>>>(qkv, stats, ctxp);
    ctx_reduce<<<dim3(256), 256, 0, stream>>>(ctxp, stats, ctxT);
    pv_fused<<<dim3(L / 256, 64), 256, 0, stream>>>(qkv, ctxT);

    // y[b][l][d] = sum_c outT[b][l][c] * Wout[d][c] + bout[d]  (M=4096, N=512, K=512), f32 out
    const __bf16* outT = qkv + (size_t)512 * L;
    gemm_bf16_mfma<4096, 512, 512, float><<<dim3(512 / 128, 4096 / 128, 8), 256, 0, stream>>>(
        outT, (size_t)1536 * L, Wob, 0, y, (size_t)4096 * 512, bout);
}